// Round 8
// baseline (237.663 us; speedup 1.0000x reference)
//
#include <hip/hip_runtime.h>

// VQ-VAE VectorQuantizer forward, MI355X (gfx950), fp32.
// N=32768 points x D=64 dims, K=1024 codes.
// Out: [0]=loss, [1..QE]=quantized [B,D,H,W], [+..]=indices [B,H*W] as f32.
//
// R8: FORCED scalar-pipe e-stream. R6/R7 proved the compiler never
// scalarizes the uniform eT loads (noclobber analysis punts) -> each became
// a per-lane VMEM load + addr VALU (VALUBusy 69% at 3.2x FMA floor). Now the
// eT row chunk (16 codes x 1 dim) is loaded with hand-written
// s_load_dwordx16 into SGPRs: one wave-instruction on the scalar pipe per
// 16 fmac. SMEM returns out-of-order -> only lgkmcnt(0) is safe: 4 buffers
// (2 pairs), wait(0)+issue-next-pair+compute ping-pong hides latency.
// Dot chains d-sequential 0..63 = bit-identical rounding to R1-R7.
// Combine via packed (dist<<32|idx) u64 atomicMin (tie -> lower idx = np
// first-argmin; 0xAA ws poison = +inf, keys need no init).

constexpr int D_   = 64;
constexpr int HW   = 1024;     // H*W
constexpr int CSL  = 128;      // codes per slice (K-split 8)
constexpr int PTS2 = 64;       // points per epilogue block
constexpr int SP   = 68;       // epilogue xT row stride
constexpr int QE   = 2097152;
constexpr int IDX_OFF = 1 + QE;

typedef float f16v __attribute__((ext_vector_type(16)));

#define SLOAD16(dst, addr) \
  asm volatile("s_load_dwordx16 %0, %1, 0x0" : "=s"(dst) : "s"(addr))
#define SWAIT0_2(a, b) \
  asm volatile("s_waitcnt lgkmcnt(0)" : "+s"(a), "+s"(b))

// ---- prep: transpose emb -> eT[64][1024], e2 (R1 expression), zero acc ----
__global__ __launch_bounds__(256) void vq_prep_kernel(
    const float* __restrict__ emb, float* __restrict__ eT,
    float* __restrict__ e2, float* __restrict__ loss_acc,
    unsigned* __restrict__ cnt) {
  __shared__ float tile[64 * 65];
  const int t  = threadIdx.x;
  const int k0 = blockIdx.x * 64;          // 16 blocks x 64 codes

  if (blockIdx.x == 0 && t == 0) { loss_acc[0] = 0.0f; cnt[0] = 0u; }

#pragma unroll
  for (int i = 0; i < 4; ++i) {
    int f = t + i * 256;                   // 0..1023 float4s
    int kl = f >> 4, d4 = f & 15;
    float4 v = *(const float4*)(emb + (k0 + kl) * 64 + d4 * 4);
    tile[kl * 65 + d4 * 4 + 0] = v.x;
    tile[kl * 65 + d4 * 4 + 1] = v.y;
    tile[kl * 65 + d4 * 4 + 2] = v.z;
    tile[kl * 65 + d4 * 4 + 3] = v.w;
  }
  __syncthreads();

#pragma unroll
  for (int i = 0; i < 16; ++i) {
    int f = t + i * 256;                   // 0..4095
    int d = f >> 6, kl = f & 63;
    eT[d * 1024 + k0 + kl] = tile[kl * 65 + d];
  }

  // e2 — expression identical to R1 (rounding!)
  if (t < 64) {
    const float4* e4 = (const float4*)(emb + (k0 + t) * 64);
    float s = 0.f;
#pragma unroll
    for (int q = 0; q < 16; ++q) {
      float4 v = e4[q];
      s += v.x * v.x; s += v.y * v.y; s += v.z * v.z; s += v.w * v.w;
    }
    e2[k0 + t] = s;
  }
}

// ---- distance + per-slice argmin: e via forced s_load_dwordx16 ----
__global__ __launch_bounds__(256, 4) void vq_dist_kernel(
    const float* __restrict__ in, const float* __restrict__ eTw,
    const float* __restrict__ e2g, unsigned long long* __restrict__ keys) {
  const int t     = threadIdx.x;
  const int blk   = blockIdx.x;        // 1024 = 128 ptiles x 8 slices
  const int ptile = blk >> 3;          // 256 points each
  const int kb    = (blk & 7) * CSL;
  const int b     = ptile >> 2;        // 4 ptiles per image
  const int hw    = (ptile & 3) * 256 + t;
  const float* xp = in + b * (D_ * HW) + hw;

  // x2: sequential-d fmaf chain — value-identical to R1-R7
  float x2 = 0.f;
#pragma unroll
  for (int d = 0; d < 64; ++d) { float xv = xp[d * HW]; x2 = fmaf(xv, xv, x2); }

  float minv = 3.4e38f;
  int   mini = 0;

  // 8 tiles of 16 codes; per d: 1 s_load_dwordx16 (wave-uniform eT row chunk,
  // scalar pipe) + 1 coalesced x dword + 16 v_fmac (v,s,v).
#pragma unroll 1
  for (int tl = 0; tl < 8; ++tl) {
    const float* et = eTw + kb + tl * 16;   // row d at et + d*1024
    float dot[16];
#pragma unroll
    for (int j = 0; j < 16; ++j) dot[j] = 0.f;

    f16v ea0, ea1, eb0, eb1;
    SLOAD16(ea0, et);                       // d=0
    SLOAD16(ea1, et + 1024);                // d=1

#pragma unroll
    for (int r = 0; r < 16; ++r) {          // d = 4r .. 4r+3
      const int d = 4 * r;
      SWAIT0_2(ea0, ea1);                   // pair A landed (safe: lgkmcnt(0))
      SLOAD16(eb0, et + (d + 2) * 1024);    // issue pair B (flies under A's fmacs)
      SLOAD16(eb1, et + (d + 3) * 1024);
      float xd0 = xp[(d + 0) * HW];
      float xd1 = xp[(d + 1) * HW];
#pragma unroll
      for (int j = 0; j < 16; ++j) dot[j] = fmaf(xd0, ea0[j], dot[j]);
#pragma unroll
      for (int j = 0; j < 16; ++j) dot[j] = fmaf(xd1, ea1[j], dot[j]);
      SWAIT0_2(eb0, eb1);                   // pair B landed
      if (r < 15) {
        SLOAD16(ea0, et + (d + 4) * 1024);  // issue next pair A
        SLOAD16(ea1, et + (d + 5) * 1024);
      }
      float xd2 = xp[(d + 2) * HW];
      float xd3 = xp[(d + 3) * HW];
#pragma unroll
      for (int j = 0; j < 16; ++j) dot[j] = fmaf(xd2, eb0[j], dot[j]);
#pragma unroll
      for (int j = 0; j < 16; ++j) dot[j] = fmaf(xd3, eb1[j], dot[j]);
    }

    // fold u = fl(fl(x2-2dot)+e2) — identical expression/order to R1-R7
#pragma unroll
    for (int j = 0; j < 16; ++j) {
      float u = fmaf(-2.f, dot[j], x2) + e2g[kb + tl * 16 + j];
      int cg = kb + tl * 16 + j;            // ascending
      if (u < minv) { minv = u; mini = cg; }   // strict <: first-min
    }
  }

  // dist > 0 -> IEEE order == unsigned order; low 32 = idx -> tie to lower idx
  unsigned long long key =
      (((unsigned long long)__float_as_uint(minv)) << 32) | (unsigned)mini;
  atomicMin(&keys[ptile * 256 + t], key);      // 0xAA.. poison acts as +inf
}

// ---- epilogue: gather, loss, straight-through quantized, indices ----
__global__ __launch_bounds__(256) void vq_epi_kernel(
    const float* __restrict__ in, const float* __restrict__ emb,
    const unsigned long long* __restrict__ keys, float* __restrict__ out,
    float* __restrict__ loss_acc, unsigned* __restrict__ cnt) {
  __shared__ float xT[D_ * SP];     // [d][p]; later holds ST values
  __shared__ int   idx_sel[PTS2];
  __shared__ float redbuf[4];

  const int t   = threadIdx.x;
  const int blk = blockIdx.x;       // 512 blocks, 64 points each
  const int b   = blk >> 4;         // 16 blocks per image
  const int hw0 = (blk & 15) * PTS2;
  const float* inb = in + b * (D_ * HW) + hw0;

#pragma unroll
  for (int i = 0; i < 4; ++i) {
    int fi = t + i * 256;                 // 0..1023 float4s
    int d = fi >> 4, p4 = fi & 15;
    *(float4*)(&xT[d * SP + p4 * 4]) = *(const float4*)(inb + d * HW + p4 * 4);
  }
  if (t < PTS2) {
    int ix = (int)(unsigned)(keys[blk * PTS2 + t] & 0xFFFFFFFFull);
    idx_sel[t] = ix;
    out[IDX_OFF + blk * PTS2 + t] = (float)ix;   // coalesced
  }
  __syncthreads();

  // gather codes, loss partial, overwrite xT with x + (q - x)  (R4-R7 proven)
  float lp = 0.f;
#pragma unroll
  for (int i = 0; i < 4; ++i) {
    int fi = t + i * 256;                 // 0..1023
    int p = fi & 63, qd = fi >> 6;        // p contiguous per wave
    int cidx = idx_sel[p];
    float4 q = *(const float4*)(emb + cidx * 64 + qd * 4);
    float xv0 = xT[(qd * 4 + 0) * SP + p];
    float xv1 = xT[(qd * 4 + 1) * SP + p];
    float xv2 = xT[(qd * 4 + 2) * SP + p];
    float xv3 = xT[(qd * 4 + 3) * SP + p];
    float d0 = q.x - xv0, d1 = q.y - xv1, d2 = q.z - xv2, d3 = q.w - xv3;
    lp = fmaf(d0, d0, lp); lp = fmaf(d1, d1, lp);
    lp = fmaf(d2, d2, lp); lp = fmaf(d3, d3, lp);
    xT[(qd * 4 + 0) * SP + p] = xv0 + d0;
    xT[(qd * 4 + 1) * SP + p] = xv1 + d1;
    xT[(qd * 4 + 2) * SP + p] = xv2 + d2;
    xT[(qd * 4 + 3) * SP + p] = xv3 + d3;
  }

  // loss: wave -> block -> one device atomic; last block finalizes out[0]
#pragma unroll
  for (int off = 1; off < 64; off <<= 1) lp += __shfl_xor(lp, off);
  if ((t & 63) == 0) redbuf[t >> 6] = lp;
  __syncthreads();   // also orders xT rewrites before the stores below
  if (t == 0) {
    atomicAdd(loss_acc, redbuf[0] + redbuf[1] + redbuf[2] + redbuf[3]);
    __threadfence();
    unsigned old = atomicAdd(cnt, 1u);
    if (old == 511u) {
      __threadfence();
      float total = atomicAdd(loss_acc, 0.0f);  // coherent read-back
      float m = total * (1.0f / 2097152.0f);
      out[0] = m + 0.25f * m;                   // ref op order
    }
  }

  // quantized output [B,D,H,W]: scalar coalesced stores (out+1 is 4B-aligned)
  float* outq = out + 1 + b * (D_ * HW) + hw0;
#pragma unroll
  for (int i = 0; i < 16; ++i) {
    int oi = t + i * 256;                 // 0..4095
    int d = oi >> 6, p = oi & 63;
    outq[d * HW + p] = xT[d * SP + p];
  }
}

extern "C" void kernel_launch(void* const* d_in, const int* in_sizes, int n_in,
                              void* d_out, int out_size, void* d_ws, size_t ws_size,
                              hipStream_t stream) {
  const float* in  = (const float*)d_in[0];
  const float* emb = (const float*)d_in[1];
  float* out = (float*)d_out;
  float*    loss_acc = (float*)d_ws;                                // ws[0]
  unsigned* cnt      = (unsigned*)d_ws + 4;                         // ws+16B
  float*    e2g      = (float*)((char*)d_ws + 256);                 // 4 KB
  float*    eT       = (float*)((char*)d_ws + 8192);                // 256 KB
  unsigned long long* keys =
      (unsigned long long*)((char*)d_ws + 8192 + 262144);           // 256 KB

  // keys need NO init: 0xAA poison > any real key (dist>0 -> top bit 0)
  vq_prep_kernel<<<16, 256, 0, stream>>>(emb, eT, e2g, loss_acc, cnt);
  vq_dist_kernel<<<1024, 256, 0, stream>>>(in, eT, e2g, keys);
  vq_epi_kernel<<<512, 256, 0, stream>>>(in, emb, keys, out, loss_acc, cnt);
}

// Round 9
// 145.341 us; speedup vs baseline: 1.6352x; 1.6352x over previous
//
#include <hip/hip_runtime.h>

// VQ-VAE VectorQuantizer forward, MI355X (gfx950), fp32.
// N=32768 points x D=64 dims, K=1024 codes.
// Out: [0]=loss, [1..QE]=quantized [B,D,H,W], [+..]=indices [B,H*W] as f32.
//
// R9: R5's proven LDS 8x8 structure, staging waste removed. Scalar-pipe e
// (R6/R7/R8) is dead: compiler won't scalarize; forced s_load thrashes K$.
// R5's 72us = 41us inner ds_read budget + ~30us in-kernel e-transpose
// (8192 scalar ds_writes/block + 4.78M conflict cyc). Now a prep kernel
// pre-transposes emb into ws in the EXACT final LDS image (bank swizzle
// baked in: float4-unit of (kg,q) at slot (kg&7)+8*((kg>>3)+2q) -> every
// inner b128 is 2-way-per-quad = free), so dist staging is a contiguous
// vector copy. x stages as a plain row copy (stride 128, frag reads hit 4
// distinct quads -> conflict-free, no pad). All numerics (R1 fmaf chains,
// fold expr, ascending-k strict <, packed u64 atomicMin w/ 0xAA=+inf)
// verbatim from 6 consecutive absmax-0 rounds.

constexpr int D_   = 64;
constexpr int HW   = 1024;     // H*W
constexpr int PTS  = 128;      // points per dist block
constexpr int CSL  = 128;      // codes per slice (K-split 8)
constexpr int PTS2 = 64;       // points per epilogue block
constexpr int SP   = 68;       // epilogue xT row stride
constexpr int QE   = 2097152;
constexpr int IDX_OFF = 1 + QE;

// ---- prep: emb -> eTs[slice][d][swizzled 128-float row] + e2 + zero acc ----
__global__ __launch_bounds__(256) void vq_prep_kernel(
    const float* __restrict__ emb, float* __restrict__ eTs,
    float* __restrict__ e2, float* __restrict__ loss_acc,
    unsigned* __restrict__ cnt) {
  __shared__ float tile[64 * 65];
  const int t  = threadIdx.x;
  const int k0 = blockIdx.x * 64;          // 16 blocks x 64 codes

  if (blockIdx.x == 0 && t == 0) { loss_acc[0] = 0.0f; cnt[0] = 0u; }

  // load 64 codes x 64 dims, coalesced float4 (R7-proven)
#pragma unroll
  for (int i = 0; i < 4; ++i) {
    int f = t + i * 256;                   // 0..1023 float4s
    int kl = f >> 4, d4 = f & 15;
    float4 v = *(const float4*)(emb + (k0 + kl) * 64 + d4 * 4);
    tile[kl * 65 + d4 * 4 + 0] = v.x;
    tile[kl * 65 + d4 * 4 + 1] = v.y;
    tile[kl * 65 + d4 * 4 + 2] = v.z;
    tile[kl * 65 + d4 * 4 + 3] = v.w;
  }
  __syncthreads();

  // scatter transposed+swizzled: code k, dim d -> eTs[s][d*128 + pos]
#pragma unroll
  for (int i = 0; i < 16; ++i) {
    int f = t + i * 256;                   // 0..4095
    int d = f >> 6, klb = f & 63;
    int k  = k0 + klb;
    int s  = k >> 7, kl = k & 127;
    int kg = kl >> 3, w = kl & 7, q = w >> 2, j = w & 3;
    int u  = (kg & 7) + 8 * ((kg >> 3) + 2 * q);   // unit slot 0..31
    eTs[s * 8192 + d * 128 + 4 * u + j] = tile[klb * 65 + d];
  }

  // e2 — expression identical to R1 (rounding!)
  if (t < 64) {
    const float4* e4 = (const float4*)(emb + (k0 + t) * 64);
    float s = 0.f;
#pragma unroll
    for (int q = 0; q < 16; ++q) {
      float4 v = e4[q];
      s += v.x * v.x; s += v.y * v.y; s += v.z * v.z; s += v.w * v.w;
    }
    e2[k0 + t] = s;
  }
}

// ---- distance + per-slice argmin: pre-staged tiles, barrier-light ----
__global__ __launch_bounds__(256, 2) void vq_dist_kernel(
    const float* __restrict__ in, const float* __restrict__ eTs,
    const float* __restrict__ e2g, unsigned long long* __restrict__ keys) {
  __shared__ float xT[D_ * 128];    // [d][p] plain rows, 32 KB
  __shared__ float eT[D_ * 128];    // [d][swizzled code units], 32 KB
  __shared__ float e2c[CSL];
  __shared__ float x2s[PTS];

  const int t     = threadIdx.x;
  const int kg    = t & 15;         // code group: 8 codes
  const int ptg   = t >> 4;         // point group: 8 points (16 groups)
  const int blk   = blockIdx.x;     // 2048 = 256 ptiles x 8 slices
  const int ptile = blk >> 3;
  const int kb    = (blk & 7) * CSL;
  const int b     = ptile >> 3;     // 8 ptiles per image
  const int hw0   = (ptile & 7) * PTS;
  const float* inb = in + b * (D_ * HW) + hw0;

  // stage x: plain row copy (row d = 512 B contiguous), b128 writes free
#pragma unroll
  for (int i = 0; i < 8; ++i) {
    int f = t + i * 256;                  // 0..2047 float4s
    int d = f >> 5, c = f & 31;
    *(float4*)(&xT[d * 128 + 4 * c]) = *(const float4*)(inb + d * HW + 4 * c);
  }
  // stage e: contiguous copy of the pre-swizzled slice image
  {
    const float4* src = (const float4*)(eTs + (blk & 7) * 8192);
    float4* dst = (float4*)eT;
#pragma unroll
    for (int i = 0; i < 8; ++i) dst[t + i * 256] = src[t + i * 256];
  }
  if (t < CSL) e2c[t] = e2g[kb + t];
  __syncthreads();

  // x2[p]: sequential-d fmaf chain — value-identical to R1-R8
  if (t < PTS) {
    float s = 0.f;
#pragma unroll 8
    for (int d = 0; d < D_; ++d) { float xv = xT[d * 128 + t]; s = fmaf(xv, xv, s); }
    x2s[t] = s;
  }
  __syncthreads();

  float x2r[8];
  {
    float4 xa = *(const float4*)&x2s[ptg * 8];
    float4 xb = *(const float4*)&x2s[ptg * 8 + 4];
    x2r[0]=xa.x; x2r[1]=xa.y; x2r[2]=xa.z; x2r[3]=xa.w;
    x2r[4]=xb.x; x2r[5]=xb.y; x2r[6]=xb.z; x2r[7]=xb.w;
  }

  // frag offsets: x hits 4 distinct quads; e units 2-way-per-quad (free)
  const int xo  = 8 * ptg;
  const int eo0 = 4 * ((kg & 7) + 8 * (kg >> 3));        // codes 8kg+0..3
  const int eo1 = 4 * ((kg & 7) + 8 * ((kg >> 3) + 2));  // codes 8kg+4..7

  float acc[8][8];
#pragma unroll
  for (int i = 0; i < 8; ++i)
#pragma unroll
    for (int j = 0; j < 8; ++j) acc[i][j] = 0.f;

  // barrier-free inner loop: 4 b128 + 64 fmac per d
#pragma unroll 4
  for (int d = 0; d < D_; ++d) {
    float4 xa = *(const float4*)&xT[d * 128 + xo];
    float4 xb = *(const float4*)&xT[d * 128 + xo + 4];
    float4 e0 = *(const float4*)&eT[d * 128 + eo0];
    float4 e1 = *(const float4*)&eT[d * 128 + eo1];
    float xf[8] = {xa.x, xa.y, xa.z, xa.w, xb.x, xb.y, xb.z, xb.w};
    float ef[8] = {e0.x, e0.y, e0.z, e0.w, e1.x, e1.y, e1.z, e1.w};
#pragma unroll
    for (int i = 0; i < 8; ++i)
#pragma unroll
      for (int j = 0; j < 8; ++j)
        acc[i][j] = fmaf(xf[i], ef[j], acc[i][j]);
  }

  // fold u = fl(fl(x2-2dot)+e2) — identical expression/order to R1-R8
  float minv[8]; int mini[8];
#pragma unroll
  for (int i = 0; i < 8; ++i) { minv[i] = 3.4e38f; mini[i] = 0; }
#pragma unroll
  for (int j = 0; j < 8; ++j) {
    int cg = kb + kg * 8 + j;             // ascending within thread
    float e2v = e2c[kg * 8 + j];
#pragma unroll
    for (int i = 0; i < 8; ++i) {
      float u = fmaf(-2.f, acc[i][j], x2r[i]) + e2v;
      if (u < minv[i]) { minv[i] = u; mini[i] = cg; }   // strict <: first-min
    }
  }

  // packed key: dist>0 -> IEEE==unsigned order; low32=idx -> tie to lower idx
#pragma unroll
  for (int i = 0; i < 8; ++i) {
    unsigned long long key =
        (((unsigned long long)__float_as_uint(minv[i])) << 32) |
        (unsigned)mini[i];
#pragma unroll
    for (int off = 1; off < 16; off <<= 1) {
      unsigned long long ko = __shfl_xor(key, off);
      if (ko < key) key = ko;
    }
    if (kg == 0)
      atomicMin(&keys[ptile * PTS + ptg * 8 + i], key); // 0xAA poison = +inf
  }
}

// ---- epilogue: gather, loss, straight-through quantized, indices ----
__global__ __launch_bounds__(256) void vq_epi_kernel(
    const float* __restrict__ in, const float* __restrict__ emb,
    const unsigned long long* __restrict__ keys, float* __restrict__ out,
    float* __restrict__ loss_acc, unsigned* __restrict__ cnt) {
  __shared__ float xT[D_ * SP];     // [d][p]; later holds ST values
  __shared__ int   idx_sel[PTS2];
  __shared__ float redbuf[4];

  const int t   = threadIdx.x;
  const int blk = blockIdx.x;       // 512 blocks, 64 points each
  const int b   = blk >> 4;         // 16 blocks per image
  const int hw0 = (blk & 15) * PTS2;
  const float* inb = in + b * (D_ * HW) + hw0;

#pragma unroll
  for (int i = 0; i < 4; ++i) {
    int fi = t + i * 256;                 // 0..1023 float4s
    int d = fi >> 4, p4 = fi & 15;
    *(float4*)(&xT[d * SP + p4 * 4]) = *(const float4*)(inb + d * HW + p4 * 4);
  }
  if (t < PTS2) {
    int ix = (int)(unsigned)(keys[blk * PTS2 + t] & 0xFFFFFFFFull);
    idx_sel[t] = ix;
    out[IDX_OFF + blk * PTS2 + t] = (float)ix;   // coalesced
  }
  __syncthreads();

  // gather codes, loss partial, overwrite xT with x + (q - x)  (R4-R8 proven)
  float lp = 0.f;
#pragma unroll
  for (int i = 0; i < 4; ++i) {
    int fi = t + i * 256;                 // 0..1023
    int p = fi & 63, qd = fi >> 6;        // p contiguous per wave
    int cidx = idx_sel[p];
    float4 q = *(const float4*)(emb + cidx * 64 + qd * 4);
    float xv0 = xT[(qd * 4 + 0) * SP + p];
    float xv1 = xT[(qd * 4 + 1) * SP + p];
    float xv2 = xT[(qd * 4 + 2) * SP + p];
    float xv3 = xT[(qd * 4 + 3) * SP + p];
    float d0 = q.x - xv0, d1 = q.y - xv1, d2 = q.z - xv2, d3 = q.w - xv3;
    lp = fmaf(d0, d0, lp); lp = fmaf(d1, d1, lp);
    lp = fmaf(d2, d2, lp); lp = fmaf(d3, d3, lp);
    xT[(qd * 4 + 0) * SP + p] = xv0 + d0;
    xT[(qd * 4 + 1) * SP + p] = xv1 + d1;
    xT[(qd * 4 + 2) * SP + p] = xv2 + d2;
    xT[(qd * 4 + 3) * SP + p] = xv3 + d3;
  }

  // loss: wave -> block -> one device atomic; last block finalizes out[0]
#pragma unroll
  for (int off = 1; off < 64; off <<= 1) lp += __shfl_xor(lp, off);
  if ((t & 63) == 0) redbuf[t >> 6] = lp;
  __syncthreads();   // also orders xT rewrites before the stores below
  if (t == 0) {
    atomicAdd(loss_acc, redbuf[0] + redbuf[1] + redbuf[2] + redbuf[3]);
    __threadfence();
    unsigned old = atomicAdd(cnt, 1u);
    if (old == 511u) {
      __threadfence();
      float total = atomicAdd(loss_acc, 0.0f);  // coherent read-back
      float m = total * (1.0f / 2097152.0f);
      out[0] = m + 0.25f * m;                   // ref op order
    }
  }

  // quantized output [B,D,H,W]: scalar coalesced stores (out+1 is 4B-aligned)
  float* outq = out + 1 + b * (D_ * HW) + hw0;
#pragma unroll
  for (int i = 0; i < 16; ++i) {
    int oi = t + i * 256;                 // 0..4095
    int d = oi >> 6, p = oi & 63;
    outq[d * HW + p] = xT[d * SP + p];
  }
}

extern "C" void kernel_launch(void* const* d_in, const int* in_sizes, int n_in,
                              void* d_out, int out_size, void* d_ws, size_t ws_size,
                              hipStream_t stream) {
  const float* in  = (const float*)d_in[0];
  const float* emb = (const float*)d_in[1];
  float* out = (float*)d_out;
  float*    loss_acc = (float*)d_ws;                                // ws[0]
  unsigned* cnt      = (unsigned*)d_ws + 4;                         // ws+16B
  float*    e2g      = (float*)((char*)d_ws + 256);                 // 4 KB
  float*    eTs      = (float*)((char*)d_ws + 8192);                // 256 KB
  unsigned long long* keys =
      (unsigned long long*)((char*)d_ws + 8192 + 262144);           // 256 KB

  // keys need NO init: 0xAA poison > any real key (dist>0 -> top bit 0)
  vq_prep_kernel<<<16, 256, 0, stream>>>(emb, eTs, e2g, loss_acc, cnt);
  vq_dist_kernel<<<2048, 256, 0, stream>>>(in, eTs, e2g, keys);
  vq_epi_kernel<<<512, 256, 0, stream>>>(in, emb, keys, out, loss_acc, cnt);
}